// Round 10
// baseline (459.367 us; speedup 1.0000x reference)
//
#include <hip/hip_runtime.h>
#include <hip/hip_bf16.h>

#define BB 16
#define NPG 512
#define CC 128
#define HH 8
#define LL 4
#define FFN 512
#define NCLS 4
#define DD 16
#define TT 513            // NPG + 1
#define EE 131072         // B * 8192
#define NNODES 8192       // B * NPG
#define ROWS (BB * TT)    // 8208 CSR rows keyed by (g, sl=query)
#define ECAP 64           // entries per bucket; Poisson(16), P(>=64) ~ 3e-22
#define SP 544            // padded s extent (34 tiles of 16)
#define BSTR 292          // bias strip stride (floats), mult of 4 for b128

static constexpr size_t XROWS = (size_t)BB * TT;   // 8208 (= 513 * 16 exactly)
static constexpr size_t XSZ   = XROWS * CC;        // 1,050,624
static constexpr size_t VTSZ  = (size_t)BB * HH * DD * SP;  // 1,114,112

typedef unsigned short ushort_t;
typedef __attribute__((ext_vector_type(8))) short short8;
typedef __attribute__((ext_vector_type(4))) float floatx4;

__device__ __forceinline__ float gelu_exact(float v) {
    return 0.5f * v * (1.0f + erff(v * 0.70710678118654752440f));
}
__device__ __forceinline__ ushort_t f2bf(float f) {
    union { float f; unsigned u; } c; c.f = f;
    unsigned u = c.u;
    return (ushort_t)((u + 0x7FFFu + ((u >> 16) & 1u)) >> 16);   // RNE
}
// XOR-swizzled LDS offset (16B granules); stride in shorts, multiple of 8
__device__ __forceinline__ int swz(int row, int col, int stride) {
    int kb = col >> 3;
    return row * stride + (((kb ^ (row & 7)) << 3) | (col & 7));
}

// ---- QKV stage (8-wave form): hs (swizzled 16x128 ln1 tile) -> qb, kb, vt ----
// Wave covers 16 cols (c = wave*16+lq) of each of Q/K/V for rows m0..m0+15.
__device__ __forceinline__ void qkv_stage8(const ushort_t* hs,
                                           const ushort_t* Wtq, const float* bq_,
                                           const ushort_t* Wtk, const float* bk_,
                                           const ushort_t* Wtv, const float* bv_,
                                           ushort_t* qb, ushort_t* kb, ushort_t* vt,
                                           int m0, int wave, int lq, int quad) {
    const short* hsS = (const short*)hs;
    int c = wave * 16 + lq;
    const short* Ws[3] = {(const short*)Wtq, (const short*)Wtk, (const short*)Wtv};
    const float* bs[3] = {bq_, bk_, bv_};
    size_t rB = (size_t)c * CC;

    #pragma unroll
    for (int m = 0; m < 3; ++m) {
        const short* W = Ws[m];
        floatx4 a0 = {0.f,0.f,0.f,0.f};
        #pragma unroll
        for (int k0 = 0; k0 < CC; k0 += 32) {
            short8 af = *(const short8*)(hsS + swz(lq, k0 + quad * 8, 128));
            short8 b0 = *(const short8*)(W + rB + k0 + quad * 8);
            a0 = __builtin_amdgcn_mfma_f32_16x16x32_bf16(af, b0, a0, 0, 0, 0);
        }
        float bvv = bs[m][c];
        #pragma unroll
        for (int rg = 0; rg < 4; ++rg) {
            int r = m0 + quad * 4 + rg;
            float v0 = a0[rg] + bvv;
            if (m == 0) {        // Q: fold 1/sqrt(D)=0.25 (exact)
                qb[(size_t)r * CC + c] = f2bf(v0 * 0.25f);
            } else if (m == 1) { // K
                kb[(size_t)r * CC + c] = f2bf(v0);
            } else {             // V, written transposed VT[bh][d][s]
                int bg = r / TT;
                int s = r - bg * TT;
                vt[((size_t)(bg * HH + (c >> 4)) * DD + (c & 15)) * SP + s] = f2bf(v0);
            }
        }
    }
}

// ---------------- degree count + query-keyed CSR build (merged) ----------------
__global__ __launch_bounds__(256) void deg_csr_kernel(const int* __restrict__ ei,
                                                      const int* __restrict__ ea,
                                                      int* __restrict__ deg_in,
                                                      int* __restrict__ deg_out,
                                                      int* __restrict__ cnt,
                                                      int* __restrict__ ebuf) {
    int e = blockIdx.x * 256 + threadIdx.x;
    if (e >= EE) return;
    int src = ei[e], dst = ei[EE + e];
    atomicAdd(&deg_out[src], 1);
    atomicAdd(&deg_in[dst], 1);
    int g = src >> 9;
    int sl = src - (g << 9) + 1;     // query index 1..512
    int dl = dst - (g << 9) + 1;     // key   index 1..512
    int a = ea[e];
    a = (a < 0) ? 0 : (a > 9 ? 9 : a);
    a += 1;                          // ebt row 1..10
    int row = g * TT + sl;           // query-keyed bucket
    int pos = atomicAdd(&cnt[row], 1);
    if (pos < ECAP) ebuf[(size_t)row * ECAP + pos] = dl | (a << 16);
}

// ---------------- node encode + graph token ----------------
__global__ __launch_bounds__(256) void encode_kernel(const float* __restrict__ nf,
                                                     const float* __restrict__ Wn,
                                                     const float* __restrict__ bn,
                                                     const float* __restrict__ gt,
                                                     const float* __restrict__ ide,
                                                     const float* __restrict__ ode,
                                                     const int* __restrict__ deg_in,
                                                     const int* __restrict__ deg_out,
                                                     float* __restrict__ x) {
    int gid = blockIdx.x * 256 + threadIdx.x;
    if (gid >= (int)(XROWS * CC)) return;
    int c = gid & (CC - 1);
    int row = gid >> 7;
    int b = row / TT;
    int t = row - b * TT;
    float val;
    if (t == 0) {
        val = gt[c];
    } else {
        int i = b * NPG + t - 1;
        val = bn[c] + nf[i*3+0]*Wn[0*CC + c] + nf[i*3+1]*Wn[1*CC + c] + nf[i*3+2]*Wn[2*CC + c];
        int di = min(deg_in[i], 511);
        int dq = min(deg_out[i], 511);
        val += ide[(size_t)di * CC + c] + ode[(size_t)dq * CC + c];
    }
    x[(size_t)row * CC + c] = val;
}

// ---------------- LDS-tiled weight transpose + bf16: Wt[n][k] = W[k][n] ----------------
struct TrDesc {
    const float* src[24];
    ushort_t*    dst[24];
    int          K[24];
    int          N[24];
};
__global__ __launch_bounds__(256) void tr_kernel(TrDesc d) {
    int z = blockIdx.z;
    int K = d.K[z], N = d.N[z];
    int tilesN = N >> 6;
    int ntile = (K >> 6) * tilesN;
    int tile = blockIdx.x;
    if (tile >= ntile) return;
    int k0 = (tile / tilesN) << 6;
    int n0 = (tile - (tile / tilesN) * tilesN) << 6;
    const float* src = d.src[z];
    ushort_t* dst = d.dst[z];
    __shared__ float t[64][65];
    int tid = threadIdx.x;
    int c = tid & 63, rb = tid >> 6;
    #pragma unroll
    for (int kk = 0; kk < 64; kk += 4)
        t[kk + rb][c] = src[(size_t)(k0 + kk + rb) * N + n0 + c];
    __syncthreads();
    #pragma unroll
    for (int nn = 0; nn < 64; nn += 4)
        dst[(size_t)(n0 + nn + rb) * K + k0 + c] = f2bf(t[c][nn + rb]);
}

// ---------------- pre kernel: ln1(layer 0) + QKV(layer 0), 8 waves ----------------
__global__ __launch_bounds__(512) void pre_kernel(const float* __restrict__ x_,
                                                  const float* __restrict__ ln1g_,
                                                  const float* __restrict__ ln1b_,
                                                  const ushort_t* __restrict__ Wtq,
                                                  const float* __restrict__ bq_,
                                                  const ushort_t* __restrict__ Wtk,
                                                  const float* __restrict__ bk_,
                                                  const ushort_t* __restrict__ Wtv,
                                                  const float* __restrict__ bv_,
                                                  ushort_t* __restrict__ qb,
                                                  ushort_t* __restrict__ kb,
                                                  ushort_t* __restrict__ vt) {
    int m0 = blockIdx.x * 16;
    int tid = threadIdx.x;
    int wave = tid >> 6, lane = tid & 63, lq = lane & 15, quad = lane >> 4;

    __shared__ ushort_t hs[16 * 128];
    __shared__ float sred[8][16][2];

    int c = wave * 16 + lq;
    float w0[4];
    #pragma unroll
    for (int rg = 0; rg < 4; ++rg) {
        int r = m0 + quad * 4 + rg;
        w0[rg] = x_[(size_t)r * CC + c];
    }
    #pragma unroll
    for (int rg = 0; rg < 4; ++rg) {
        float s1 = w0[rg];
        float s2 = w0[rg]*w0[rg];
        #pragma unroll
        for (int m = 1; m < 16; m <<= 1) {
            s1 += __shfl_xor(s1, m, 64);
            s2 += __shfl_xor(s2, m, 64);
        }
        if (lq == 0) { sred[wave][quad*4+rg][0] = s1; sred[wave][quad*4+rg][1] = s2; }
    }
    __syncthreads();
    float g0 = ln1g_[c], lb0 = ln1b_[c];
    #pragma unroll
    for (int rg = 0; rg < 4; ++rg) {
        int row = quad * 4 + rg;
        float S1 = 0.f, S2 = 0.f;
        #pragma unroll
        for (int w = 0; w < 8; ++w) { S1 += sred[w][row][0]; S2 += sred[w][row][1]; }
        float mn = S1 * (1.0f/CC);
        float var = S2 * (1.0f/CC) - mn * mn;
        float rs = rsqrtf(var + 1e-5f);
        hs[swz(row, c, 128)] = f2bf((w0[rg] - mn) * rs * g0 + lb0);
    }
    __syncthreads();
    qkv_stage8(hs, Wtq, bq_, Wtk, bk_, Wtv, bv_, qb, kb, vt, m0, wave, lq, quad);
}

// ---------------- mega kernel (8 waves / 512 thr) ----------------
// o-proj + res + ln2 + ffn1 + gelu + ffn2 + res + ln1next + QKVnext (if doQKV)
// Block = one 16-row tile (grid 513). N=128 stages: wave slice = 16 cols.
__global__ __launch_bounds__(512) void mega_kernel(const ushort_t* __restrict__ obf,
                                                   const ushort_t* __restrict__ WtO,
                                                   const float* __restrict__ bo_,
                                                   const float* __restrict__ ln2g_,
                                                   const float* __restrict__ ln2b_,
                                                   const ushort_t* __restrict__ Wt1_,
                                                   const float* __restrict__ b1_,
                                                   const ushort_t* __restrict__ Wt2_,
                                                   const float* __restrict__ b2_,
                                                   const float* __restrict__ ln1g_,
                                                   const float* __restrict__ ln1b_,
                                                   const ushort_t* __restrict__ Wtq,
                                                   const float* __restrict__ bq_,
                                                   const ushort_t* __restrict__ Wtk,
                                                   const float* __restrict__ bk_,
                                                   const ushort_t* __restrict__ Wtv,
                                                   const float* __restrict__ bv_,
                                                   float* __restrict__ x_,
                                                   ushort_t* __restrict__ qb,
                                                   ushort_t* __restrict__ kb,
                                                   ushort_t* __restrict__ vt,
                                                   int doQKV) {
    int m0 = blockIdx.x * 16;
    int tid = threadIdx.x;
    int wave = tid >> 6, lane = tid & 63, lq = lane & 15, quad = lane >> 4;

    __shared__ ushort_t hs[16 * 128];    // ln2(h) tile then ln1next tile, swizzled
    __shared__ ushort_t ms[16 * 512];    // gelu(mid) tile, swizzled
    __shared__ float sred[8][16][2];

    int c = wave * 16 + lq;              // this wave's output col for N=128 stages
    float vv0[4];                        // o-proj residual, reused in ffn2 epilogue

    // ---- stage 1: o-proj (16x16 per wave, K=128) + res + ln2 -> hs ----
    {
        const short* Ab = (const short*)obf;
        const short* W = (const short*)WtO;
        size_t rowA = (size_t)(m0 + lq) * CC;
        size_t rB = (size_t)c * CC;
        floatx4 a0 = {0.f,0.f,0.f,0.f};
        #pragma unroll
        for (int k0 = 0; k0 < CC; k0 += 32) {
            short8 af = *(const short8*)(Ab + rowA + k0 + quad * 8);
            short8 b0 = *(const short8*)(W + rB + k0 + quad * 8);
            a0 = __builtin_amdgcn_mfma_f32_16x16x32_bf16(af, b0, a0, 0, 0, 0);
        }
        float bv0 = bo_[c];
        #pragma unroll
        for (int rg = 0; rg < 4; ++rg) {
            int r = m0 + quad * 4 + rg;
            vv0[rg] = a0[rg] + bv0 + x_[(size_t)r * CC + c];
        }
        #pragma unroll
        for (int rg = 0; rg < 4; ++rg) {
            float s1 = vv0[rg];
            float s2 = vv0[rg]*vv0[rg];
            #pragma unroll
            for (int m = 1; m < 16; m <<= 1) {
                s1 += __shfl_xor(s1, m, 64);
                s2 += __shfl_xor(s2, m, 64);
            }
            if (lq == 0) { sred[wave][quad*4+rg][0] = s1; sred[wave][quad*4+rg][1] = s2; }
        }
        __syncthreads();
        float g0 = ln2g_[c], lb0 = ln2b_[c];
        #pragma unroll
        for (int rg = 0; rg < 4; ++rg) {
            int row = quad * 4 + rg;
            float S1 = 0.f, S2 = 0.f;
            #pragma unroll
            for (int w = 0; w < 8; ++w) { S1 += sred[w][row][0]; S2 += sred[w][row][1]; }
            float mn = S1 * (1.0f/CC);
            float var = S2 * (1.0f/CC) - mn * mn;
            float rs = rsqrtf(var + 1e-5f);
            hs[swz(row, c, 128)] = f2bf((vv0[rg] - mn) * rs * g0 + lb0);
        }
    }
    __syncthreads();

    // ---- stage 2: ffn1 (wave covers mid cols wave*64..+63, K=128) + gelu -> ms ----
    {
        const short* hsS = (const short*)hs;
        const short* W = (const short*)Wt1_;
        #pragma unroll
        for (int nt = 0; nt < 2; ++nt) {
            int n = wave * 64 + nt * 32;
            size_t rB0 = (size_t)(n + lq) * CC, rB1 = (size_t)(n + 16 + lq) * CC;
            floatx4 a0 = {0.f,0.f,0.f,0.f}, a1 = a0;
            #pragma unroll
            for (int k0 = 0; k0 < CC; k0 += 32) {
                short8 af = *(const short8*)(hsS + swz(lq, k0 + quad * 8, 128));
                short8 b0 = *(const short8*)(W + rB0 + k0 + quad * 8);
                short8 b1 = *(const short8*)(W + rB1 + k0 + quad * 8);
                a0 = __builtin_amdgcn_mfma_f32_16x16x32_bf16(af, b0, a0, 0, 0, 0);
                a1 = __builtin_amdgcn_mfma_f32_16x16x32_bf16(af, b1, a1, 0, 0, 0);
            }
            float bb0 = b1_[n + lq], bb1 = b1_[n + 16 + lq];
            #pragma unroll
            for (int rg = 0; rg < 4; ++rg) {
                int row = quad * 4 + rg;
                ms[swz(row, n + lq, 512)]      = f2bf(gelu_exact(a0[rg] + bb0));
                ms[swz(row, n + 16 + lq, 512)] = f2bf(gelu_exact(a1[rg] + bb1));
            }
        }
    }
    __syncthreads();

    // ---- stage 3: ffn2 (16x16 per wave, K=512 from ms) + res + ln1next -> hs ----
    {
        const short* msS = (const short*)ms;
        const short* W = (const short*)Wt2_;
        size_t rB = (size_t)c * FFN;
        floatx4 a0 = {0.f,0.f,0.f,0.f};
        #pragma unroll 4
        for (int k0 = 0; k0 < FFN; k0 += 32) {
            short8 af = *(const short8*)(msS + swz(lq, k0 + quad * 8, 512));
            short8 b0 = *(const short8*)(W + rB + k0 + quad * 8);
            a0 = __builtin_amdgcn_mfma_f32_16x16x32_bf16(af, b0, a0, 0, 0, 0);
        }
        float bv0 = b2_[c];
        float w0[4];
        #pragma unroll
        for (int rg = 0; rg < 4; ++rg) {
            int r = m0 + quad * 4 + rg;
            w0[rg] = a0[rg] + bv0 + vv0[rg];
            x_[(size_t)r * CC + c] = w0[rg];
        }
        if (!doQKV) return;
        #pragma unroll
        for (int rg = 0; rg < 4; ++rg) {
            float s1 = w0[rg];
            float s2 = w0[rg]*w0[rg];
            #pragma unroll
            for (int m = 1; m < 16; m <<= 1) {
                s1 += __shfl_xor(s1, m, 64);
                s2 += __shfl_xor(s2, m, 64);
            }
            if (lq == 0) { sred[wave][quad*4+rg][0] = s1; sred[wave][quad*4+rg][1] = s2; }
        }
        __syncthreads();
        float g0 = ln1g_[c], lb0 = ln1b_[c];
        #pragma unroll
        for (int rg = 0; rg < 4; ++rg) {
            int row = quad * 4 + rg;
            float S1 = 0.f, S2 = 0.f;
            #pragma unroll
            for (int w = 0; w < 8; ++w) { S1 += sred[w][row][0]; S2 += sred[w][row][1]; }
            float mn = S1 * (1.0f/CC);
            float var = S2 * (1.0f/CC) - mn * mn;
            float rs = rsqrtf(var + 1e-5f);
            hs[swz(row, c, 128)] = f2bf((w0[rg] - mn) * rs * g0 + lb0);
        }
    }
    __syncthreads();

    // ---- stage 4: QKV for the next layer from hs ----
    qkv_stage8(hs, Wtq, bq_, Wtk, bk_, Wtv, bv_, qb, kb, vt, m0, wave, lq, quad);
}

// ---------------- MFMA fused attention: one block per (bh, 16-query tile) ----------------
__global__ __launch_bounds__(256) void attn_kernel(const ushort_t* __restrict__ qb,
                                                   const ushort_t* __restrict__ kb,
                                                   const ushort_t* __restrict__ vt,
                                                   const int* __restrict__ cnt,
                                                   const int* __restrict__ ebuf,
                                                   const float* __restrict__ ebt,
                                                   const float* __restrict__ vnode,
                                                   ushort_t* __restrict__ ob) {
    int bh = blockIdx.x;
    int qt = blockIdx.y;
    int b = bh >> 3, h = bh & (HH - 1);
    int tid = threadIdx.x;
    int wave = tid >> 6, lane = tid & 63, lq = lane & 15, quad = lane >> 4;

    __shared__ float arena[16 * BSTR];   // strip [q][s] (aliased by epilogue bufs)
    float* bstrip = arena;

    int qg = qt * 16 + lq;
    int qr = qg < TT ? qg : TT - 1;
    short8 qf = {0,0,0,0,0,0,0,0};
    if (quad < 2)
        qf = *(const short8*)(qb + ((size_t)(b * TT + qr)) * CC + h * DD + quad * 8);
    float vbh = vnode[h];
    int ql = tid >> 4, e0 = tid & 15;
    int qs = qt * 16 + ql;
    int crow = b * TT + (qs < TT ? qs : 0);
    int cn = (qs > 0 && qs < TT) ? min(cnt[crow], ECAP) : 0;

    const short* kbS = (const short*)kb;
    const short* vtS = (const short*)(vt + (size_t)bh * DD * SP);

    floatx4 oacc = {0.f, 0.f, 0.f, 0.f};
    float lsum = 0.f;

    #pragma unroll
    for (int ch = 0; ch < 2; ++ch) {
        int sp_lo = ch ? 9 : 0;
        int sp_hi = ch ? 17 : 9;
        int s_lo  = ch ? 288 : 0;
        int nrows = ch ? 256 : 288;

        int sp = sp_lo + wave;
        short8 af0 = {0,0,0,0,0,0,0,0}, af1 = af0, vf = af0;
        if (sp < sp_hi) {
            int st0 = sp * 2, st1 = sp * 2 + 1;
            int kr0 = min(b * TT + st0 * 16 + lq, (int)XROWS - 1);
            int kr1 = min(b * TT + st1 * 16 + lq, (int)XROWS - 1);
            if (quad < 2) {
                af0 = *(const short8*)(kbS + (size_t)kr0 * CC + h * DD + quad * 8);
                af1 = *(const short8*)(kbS + (size_t)kr1 * CC + h * DD + quad * 8);
            }
            vf = *(const short8*)(vtS + (size_t)lq * SP + sp * 32 + quad * 8);
        }

        for (int i = tid; i < 16 * BSTR / 4; i += 256)
            ((float4*)bstrip)[i] = make_float4(0.f, 0.f, 0.f, 0.f);
        __syncthreads();
        if (ch == 0 && tid < 16) {
            int q = qt * 16 + tid;
            if (q > 0 && q < TT) bstrip[tid * BSTR] = vbh;
        }
        for (int j = e0; j < cn; j += 16) {
            int e = ebuf[(size_t)crow * ECAP + j];
            int dl = e & 0xFFFF, a = e >> 16;
            int loc = dl - s_lo;
            if (loc >= 0 && loc < nrows)
                atomicAdd(&bstrip[ql * BSTR + loc], ebt[a * 8 + h]);
        }
        __syncthreads();

        for (; sp < sp_hi; sp += 4) {
            int spn = sp + 4;
            short8 nf0 = {0,0,0,0,0,0,0,0}, nf1 = nf0, nvf = nf0;
            if (spn < sp_hi) {
                int st0 = spn * 2, st1 = spn * 2 + 1;
                int kr0 = min(b * TT + st0 * 16 + lq, (int)XROWS - 1);
                int kr1 = min(b * TT + st1 * 16 + lq, (int)XROWS - 1);
                if (quad < 2) {
                    nf0 = *(const short8*)(kbS + (size_t)kr0 * CC + h * DD + quad * 8);
                    nf1 = *(const short8*)(kbS + (size_t)kr1 * CC + h * DD + quad * 8);
                }
                nvf = *(const short8*)(vtS + (size_t)lq * SP + spn * 32 + quad * 8);
            }

            unsigned pw[2][2];
            #pragma unroll
            for (int t = 0; t < 2; ++t) {
                int st = sp * 2 + t;
                floatx4 c = __builtin_amdgcn_mfma_f32_16x16x32_bf16(
                    t ? af1 : af0, qf, (floatx4){0.f, 0.f, 0.f, 0.f}, 0, 0, 0);
                float4 bi = *(const float4*)(bstrip + lq * BSTR + (st * 16 - s_lo) + quad * 4);
                float biv[4] = {bi.x, bi.y, bi.z, bi.w};
                float pr[4];
                #pragma unroll
                for (int rg = 0; rg < 4; ++rg) {
                    int s = st * 16 + quad * 4 + rg;
                    float p = 0.f;
                    if (s < TT) p = __expf(c[rg] + biv[rg]);
                    lsum += p;
                    pr[rg] = p;
                }
                pw[t][0] = (unsigned)f2bf(pr[0]) | ((unsigned)f2bf(pr[1]) << 16);
                pw[t][1] = (unsigned)f2bf(pr[2]) | ((unsigned)f2bf(pr[3]) << 16);
            }
            int srcA = lq + (((2 * quad) & 3) << 4);
            int srcB = lq + (((2 * quad + 1) & 3) << 4);
            int a00 = __shfl((int)pw[0][0], srcA, 64);
            int a01 = __shfl((int)pw[0][1], srcA, 64);
            int a10 = __shfl((int)pw[1][0], srcA, 64);
            int a11 = __shfl((int)pw[1][1], srcA, 64);
            int b00 = __shfl((int)pw[0][0], srcB, 64);
            int b01 = __shfl((int)pw[0][1], srcB, 64);
            int b10 = __shfl((int)pw[1][0], srcB, 64);
            int b11 = __shfl((int)pw[1][1], srcB, 64);
            union { int u[4]; short8 s8; } pu;
            bool lo = quad < 2;
            pu.u[0] = lo ? a00 : a10;
            pu.u[1] = lo ? a01 : a11;
            pu.u[2] = lo ? b00 : b10;
            pu.u[3] = lo ? b01 : b11;
            oacc = __builtin_amdgcn_mfma_f32_16x16x32_bf16(vf, pu.s8, oacc, 0, 0, 0);

            af0 = nf0; af1 = nf1; vf = nvf;
        }
        __syncthreads();
    }

    lsum += __shfl_xor(lsum, 16, 64);
    lsum += __shfl_xor(lsum, 32, 64);
    float* redw = arena;
    float* lsumS = arena + 1088;
    #pragma unroll
    for (int rg = 0; rg < 4; ++rg)
        redw[wave * 272 + (quad * 4 + rg) * 17 + lq] = oacc[rg];
    if (quad == 0) lsumS[wave * 16 + lq] = lsum;
    __syncthreads();

    {
        int q = tid >> 4, d = tid & 15;
        float o = 0.f, L = 0.f;
        #pragma unroll
        for (int w = 0; w < 4; ++w) {
            o += redw[w * 272 + d * 17 + q];
            L += lsumS[w * 16 + q];
        }
        int qq = qt * 16 + q;
        if (qq < TT)
            ob[((size_t)(b * TT + qq)) * CC + h * DD + d] = f2bf(o / L);
    }
}

// ---------------- final LN on graph tokens + classifier ----------------
__global__ __launch_bounds__(128) void head_kernel(const float* __restrict__ x,
                                                   const float* __restrict__ ng,
                                                   const float* __restrict__ nb,
                                                   const float* __restrict__ Wc1,
                                                   const float* __restrict__ bc1,
                                                   const float* __restrict__ Wc2,
                                                   const float* __restrict__ bc2,
                                                   float* __restrict__ out) {
    int b = blockIdx.x;
    int c = threadIdx.x;
    __shared__ float xfs[CC];
    __shared__ float c1s[64];
    __shared__ float red[4];

    float v = x[((size_t)b * TT) * CC + c];
    float s1 = v, s2 = v * v;
    #pragma unroll
    for (int m = 32; m >= 1; m >>= 1) {
        s1 += __shfl_xor(s1, m, 64);
        s2 += __shfl_xor(s2, m, 64);
    }
    int w = c >> 6;
    if ((c & 63) == 0) { red[w*2] = s1; red[w*2+1] = s2; }
    __syncthreads();
    float S1 = red[0] + red[2], S2 = red[1] + red[3];
    float mn = S1 * (1.0f/CC);
    float var = S2 * (1.0f/CC) - mn * mn;
    float rs = rsqrtf(var + 1e-5f);
    xfs[c] = (v - mn) * rs * ng[c] + nb[c];
    __syncthreads();
    if (c < 64) {
        float a = bc1[c];
        #pragma unroll 4
        for (int k = 0; k < CC; ++k) a = fmaf(xfs[k], Wc1[(size_t)k * 64 + c], a);
        c1s[c] = gelu_exact(a);
    }
    __syncthreads();
    if (c < NCLS) {
        float a = bc2[c];
        #pragma unroll 4
        for (int j = 0; j < 64; ++j) a = fmaf(c1s[j], Wc2[(size_t)j * NCLS + c], a);
        out[(size_t)b * NCLS + c] = a;
    }
}

extern "C" void kernel_launch(void* const* d_in, const int* in_sizes, int n_in,
                              void* d_out, int out_size, void* d_ws, size_t ws_size,
                              hipStream_t stream) {
    const float* node_feats = (const float*)d_in[0];
    const int*   edge_index = (const int*)d_in[1];
    const int*   edge_attr  = (const int*)d_in[2];
    const float* W_node  = (const float*)d_in[4];
    const float* b_node  = (const float*)d_in[5];
    const float* g_token = (const float*)d_in[6];
    const float* ebt     = (const float*)d_in[7];
    const float* ide     = (const float*)d_in[8];
    const float* ode     = (const float*)d_in[9];
    const float* vnode   = (const float*)d_in[10];
    const float* Wq = (const float*)d_in[11];
    const float* bq = (const float*)d_in[12];
    const float* Wk = (const float*)d_in[13];
    const float* bk = (const float*)d_in[14];
    const float* Wv = (const float*)d_in[15];
    const float* bv = (const float*)d_in[16];
    const float* Wo = (const float*)d_in[17];
    const float* bo = (const float*)d_in[18];
    const float* ln1g = (const float*)d_in[19];
    const float* ln1b = (const float*)d_in[20];
    const float* ln2g = (const float*)d_in[21];
    const float* ln2b = (const float*)d_in[22];
    const float* W1 = (const float*)d_in[23];
    const float* b1 = (const float*)d_in[24];
    const float* W2 = (const float*)d_in[25];
    const float* b2 = (const float*)d_in[26];
    const float* nfg = (const float*)d_in[27];
    const float* nfb = (const float*)d_in[28];
    const float* Wc1 = (const float*)d_in[29];
    const float* bc1 = (const float*)d_in[30];
    const float* Wc2 = (const float*)d_in[31];
    const float* bc2 = (const float*)d_in[32];
    float* out = (float*)d_out;

    // ---- workspace (all chunks 16B-aligned) ----
    char* base = (char*)d_ws;
    float* x      = (float*)base;     base += XSZ * 4;
    ushort_t* qb  = (ushort_t*)base;  base += XSZ * 2;
    ushort_t* kb  = (ushort_t*)base;  base += XSZ * 2;
    ushort_t* vt  = (ushort_t*)base;  base += VTSZ * 2;
    ushort_t* obf = (ushort_t*)base;  base += XSZ * 2;
    ushort_t* wtqkvo = (ushort_t*)base; base += (size_t)16 * 16384 * 2;
    ushort_t* wt1 = (ushort_t*)base;  base += (size_t)4 * 65536 * 2;
    ushort_t* wt2 = (ushort_t*)base;  base += (size_t)4 * 65536 * 2;
    int* deg_in  = (int*)base;        base += NNODES * 4;
    int* deg_out = (int*)base;        base += NNODES * 4;
    int* cnt     = (int*)base;        base += (size_t)ROWS * 4;
    int* ebuf    = (int*)base;        base += (size_t)ROWS * ECAP * 4;

    hipMemsetAsync(deg_in, 0, (size_t)(2 * NNODES + ROWS) * 4, stream);
    deg_csr_kernel<<<EE / 256, 256, 0, stream>>>(edge_index, edge_attr,
                                                 deg_in, deg_out, cnt, ebuf);
    encode_kernel<<<(int)((XROWS * CC + 255) / 256), 256, 0, stream>>>(
        node_feats, W_node, b_node, g_token, ide, ode, deg_in, deg_out, x);

    TrDesc td;
    for (int l = 0; l < LL; ++l) {
        const float* srcs[4] = {Wq + (size_t)l*CC*CC, Wk + (size_t)l*CC*CC,
                                Wv + (size_t)l*CC*CC, Wo + (size_t)l*CC*CC};
        for (int k = 0; k < 4; ++k) {
            int slot = k * 4 + l;
            td.src[slot] = srcs[k];
            td.dst[slot] = wtqkvo + (size_t)slot * 16384;
            td.K[slot] = CC; td.N[slot] = CC;
        }
        td.src[16 + l] = W1 + (size_t)l*CC*FFN;
        td.dst[16 + l] = wt1 + (size_t)l*65536;
        td.K[16 + l] = CC; td.N[16 + l] = FFN;
        td.src[20 + l] = W2 + (size_t)l*FFN*CC;
        td.dst[20 + l] = wt2 + (size_t)l*65536;
        td.K[20 + l] = FFN; td.N[20 + l] = CC;
    }
    tr_kernel<<<dim3(16, 1, 24), 256, 0, stream>>>(td);

    const int MT16 = (int)(XROWS / 16);   // 513 m-tiles of 16 rows (exact)

    // layer 0: ln1 + QKV fused
    pre_kernel<<<MT16, 512, 0, stream>>>(
        x, ln1g, ln1b,
        wtqkvo + (size_t)(0*4+0)*16384, bq,
        wtqkvo + (size_t)(1*4+0)*16384, bk,
        wtqkvo + (size_t)(2*4+0)*16384, bv,
        qb, kb, vt);

    for (int l = 0; l < LL; ++l) {
        attn_kernel<<<dim3(BB*HH, 33), 256, 0, stream>>>(
            qb, kb, vt, cnt, ebuf, ebt, vnode, obf);

        int ln = (l + 1) % LL;   // next layer (unused when l==LL-1)
        mega_kernel<<<MT16, 512, 0, stream>>>(
            obf,
            wtqkvo + (size_t)(3*4+l)*16384, bo + l*CC,
            ln2g + l*CC, ln2b + l*CC,
            wt1 + (size_t)l*65536, b1 + l*FFN,
            wt2 + (size_t)l*65536, b2 + l*CC,
            ln1g + ln*CC, ln1b + ln*CC,
            wtqkvo + (size_t)(0*4+ln)*16384, bq + ln*CC,
            wtqkvo + (size_t)(1*4+ln)*16384, bk + ln*CC,
            wtqkvo + (size_t)(2*4+ln)*16384, bv + ln*CC,
            x, qb, kb, vt,
            (l < LL-1) ? 1 : 0);
    }

    head_kernel<<<BB, 128, 0, stream>>>(x, nfg, nfb, Wc1, bc1, Wc2, bc2, out);
}